// Round 2
// baseline (762.853 us; speedup 1.0000x reference)
//
#include <hip/hip_runtime.h>

// article_concat: [256, 2048, 300] fp32  (d_in[0])
// options_concat: [256,   64, 300] fp32  (d_in[1])
// out:            [256, 600]       fp32
//
// Two-phase mean-pool (no atomics, no output memset):
//  Phase 1: grid (256 b, 8 y). Each block sums a contiguous 256-row chunk of
//    article[b]. 300 threads read the chunk as a flat float4 stream
//    (f = it*300 + t), so column j = t%75 is constant per thread -> register
//    accumulation, fully coalesced 4800 B per block-iteration. FOUR independent
//    accumulators x 4 loads x unroll 4 keep 16 nontemporal loads in flight per
//    thread. LDS-reduce the 4 row-phases, write float4 partial to d_ws.
//  Phase 2: grid (256 b), 300 threads. Thread c sums the 8 partials for
//    out[b][c] and the 64 option rows for out[b][300+c]. Every output element
//    written exactly once.

typedef float f4 __attribute__((ext_vector_type(4)));

#define B        256
#define DIM      300
#define J4       75                       // DIM/4 float4 columns
#define W_ART    2048
#define W_OPT    64
#define SPLIT    8
#define ROWS_PB  (W_ART / SPLIT)          // 256 rows per phase-1 block
#define ITERS    (ROWS_PB * J4 / DIM)     // 64 float4 loads per thread

__global__ __launch_bounds__(DIM) void art_partial_kernel(
    const f4* __restrict__ art,           // [B][2048][75]
    f4* __restrict__ part)                // [SPLIT][B][75]
{
    const int b = blockIdx.x;
    const int y = blockIdx.y;
    const int t = threadIdx.x;
    const int j = t % J4;

    // Walk a single pointer through the chunk; 4 loads per step, step = 4*DIM.
    const f4* p = art + (size_t)b * (W_ART * J4) + (size_t)y * (ROWS_PB * J4) + t;

    f4 a0 = {0.f, 0.f, 0.f, 0.f};
    f4 a1 = {0.f, 0.f, 0.f, 0.f};
    f4 a2 = {0.f, 0.f, 0.f, 0.f};
    f4 a3 = {0.f, 0.f, 0.f, 0.f};
    #pragma unroll 4
    for (int it = 0; it < ITERS; it += 4, p += 4 * DIM) {
        const f4 v0 = __builtin_nontemporal_load(&p[0 * DIM]);
        const f4 v1 = __builtin_nontemporal_load(&p[1 * DIM]);
        const f4 v2 = __builtin_nontemporal_load(&p[2 * DIM]);
        const f4 v3 = __builtin_nontemporal_load(&p[3 * DIM]);
        a0 += v0;
        a1 += v1;
        a2 += v2;
        a3 += v3;
    }
    a0 += a1;
    a2 += a3;
    a0 += a2;

    __shared__ f4 lds[DIM];
    lds[t] = a0;
    __syncthreads();
    if (t < J4) {
        const f4 r = lds[t] + lds[t + J4] + lds[t + 2 * J4] + lds[t + 3 * J4];
        part[((size_t)y * B + b) * J4 + j] = r;
    }
}

__global__ __launch_bounds__(DIM) void finalize_kernel(
    const float* __restrict__ part,       // [SPLIT][B][300]
    const float* __restrict__ opt,        // [B][64][300]
    float* __restrict__ out)              // [B][600]
{
    const int b = blockIdx.x;
    const int c = threadIdx.x;            // 0..299

    float s = 0.f;
    #pragma unroll
    for (int y = 0; y < SPLIT; ++y)
        s += part[((size_t)y * B + b) * DIM + c];

    const float* ob = opt + (size_t)b * (W_OPT * DIM) + c;
    float o0 = 0.f, o1 = 0.f, o2 = 0.f, o3 = 0.f;
    #pragma unroll 4
    for (int w = 0; w < W_OPT; w += 4) {
        o0 += __builtin_nontemporal_load(&ob[(size_t)(w + 0) * DIM]);
        o1 += __builtin_nontemporal_load(&ob[(size_t)(w + 1) * DIM]);
        o2 += __builtin_nontemporal_load(&ob[(size_t)(w + 2) * DIM]);
        o3 += __builtin_nontemporal_load(&ob[(size_t)(w + 3) * DIM]);
    }

    float* ou = out + (size_t)b * (2 * DIM);
    ou[c]       = s * (1.0f / (float)W_ART);
    ou[DIM + c] = ((o0 + o1) + (o2 + o3)) * (1.0f / (float)W_OPT);
}

extern "C" void kernel_launch(void* const* d_in, const int* in_sizes, int n_in,
                              void* d_out, int out_size, void* d_ws, size_t ws_size,
                              hipStream_t stream) {
    const f4* art = (const f4*)d_in[0];
    const float* opt = (const float*)d_in[1];
    float* out = (float*)d_out;
    f4* part = (f4*)d_ws;                 // needs SPLIT*B*300*4 = 2.4 MB of ws

    art_partial_kernel<<<dim3(B, SPLIT), dim3(DIM), 0, stream>>>(art, part);
    finalize_kernel<<<dim3(B), dim3(DIM), 0, stream>>>((const float*)part, opt, out);
}